// Round 21
// baseline (179.897 us; speedup 1.0000x reference)
//
#include <hip/hip_runtime.h>
#include <hip/hip_bf16.h>
#include <stdint.h>

#define BTOT 4096
#define RR   64
#define DIMD 128

typedef short s16x8 __attribute__((ext_vector_type(8)));
typedef float f32x4 __attribute__((ext_vector_type(4)));

__device__ __forceinline__ unsigned short f2bf(float x) {
  __hip_bfloat16 h = __float2bfloat16(x);
  return __builtin_bit_cast(unsigned short, h);
}
__device__ __forceinline__ unsigned int pk2(float lo, float hi) {
  return ((unsigned int)f2bf(hi) << 16) | (unsigned int)f2bf(lo);
}
__device__ __forceinline__ float bflo(unsigned int u) {
  return __builtin_bit_cast(float, u << 16);
}
__device__ __forceinline__ float bfhi(unsigned int u) {
  return __builtin_bit_cast(float, u & 0xFFFF0000u);
}

// ---------------------------------------------------------------------------
// Pre-kernel: qproj[b,k] = sum_d query_r[b,d]*W1[k,128+d] + b1[k]  (fp32),
// offset_emb passthrough, and blocks 0/1 emit PERMUTED+swizzled bf16 copies
// of W1a / W2 into ws. d-permutation pi(s) = 32*(s>>5) + 16*((s>>2)&1) +
// 4*((s>>3)&3) + (s&3); bank-XOR: addr = k*128 + (s ^ ((k&7)<<3)).
// [layout verified: R16/R17/R19/R20 passed absmax 0.5]
// ---------------------------------------------------------------------------
__global__ __launch_bounds__(256) void prep_kernel(
    const float* __restrict__ W1, const float* __restrict__ b1,
    const float* __restrict__ query_r, const float* __restrict__ W2,
    const float* __restrict__ offset_emb,
    float* __restrict__ qproj, unsigned short* __restrict__ w1a_t,
    unsigned short* __restrict__ w2_t, float* __restrict__ out)
{
  __shared__ float w1b[128 * 132];   // +4 pad
  __shared__ float qrs[256];
  const int tid = threadIdx.x;

  { // offset_emb passthrough (1 float4 per thread; 512 blocks cover 4096x128)
    const size_t ob = (size_t)blockIdx.x * 8 * DIMD + (size_t)tid * 4;
    *reinterpret_cast<float4*>(out + (size_t)BTOT * DIMD + ob) =
        *reinterpret_cast<const float4*>(offset_emb + ob);
  }
  { // stage W1b fp32 into padded LDS
    const int k = tid >> 1, d0 = (tid & 1) * 64;
    const float* src = W1 + k * 256 + 128 + d0;
    float* dst = &w1b[k * 132 + d0];
    #pragma unroll
    for (int i = 0; i < 64; i += 4)
      *reinterpret_cast<float4*>(dst + i) = *reinterpret_cast<const float4*>(src + i);
  }
  if (blockIdx.x < 2) { // permuted + swizzled bf16 weight tables
    const float* Wsrc = (blockIdx.x == 0) ? W1 : W2;
    unsigned short* dstw = (blockIdx.x == 0) ? w1a_t : w2_t;
    const int stride = (blockIdx.x == 0) ? 256 : 128;
    for (int i = tid; i < 128 * 128; i += 256) {
      const int k = i >> 7, s = i & 127;
      const int d = 32 * (s >> 5) + 16 * ((s >> 2) & 1) + 4 * ((s >> 3) & 3) + (s & 3);
      dstw[k * 128 + (s ^ ((k & 7) << 3))] = f2bf(Wsrc[k * stride + d]);
    }
  }
  __syncthreads();

  const int b0 = blockIdx.x * 8;
  const int k = tid & 127, bh = tid >> 7;
  for (int p = 0; p < 4; ++p) {
    const int b = b0 + p * 2;
    qrs[tid] = query_r[(size_t)(b + bh) * DIMD + k];
    __syncthreads();
    float acc = b1[k];
    const float* qq = &qrs[bh * 128];
    const float* wr = &w1b[k * 132];
    #pragma unroll
    for (int d = 0; d < 128; d += 4) {
      float4 wv = *reinterpret_cast<const float4*>(wr + d);
      float4 qv = *reinterpret_cast<const float4*>(qq + d);
      acc = fmaf(wv.x, qv.x, acc); acc = fmaf(wv.y, qv.y, acc);
      acc = fmaf(wv.z, qv.z, acc); acc = fmaf(wv.w, qv.w, acc);
    }
    qproj[(size_t)(b + bh) * DIMD + k] = acc;
    __syncthreads();
  }
}

// ---------------------------------------------------------------------------
// Main kernel: 512 blocks x 512 threads (8 waves), each wave owns ONE b.
// OCCUPANCY ROUND, AGPR-aware. 20-round model: true per-wave alloc =
// reported VGPR (64-quantized) + 64 hidden AGPR (MFMA accumulators; unified
// file). Every "clean" variant was 112-128 + 64 = 192 -> 2 waves/SIMD ->
// the 8-waves/CU, 1.57 TB/s, 130-us invariant. Fix: force reported VGPR to
// 64 so total = 128 -> 4 waves/SIMD (2 co-resident blocks x 8 waves).
//  - __launch_bounds__(512, 4): empirical cap = 512/(2*arg) = 64.
//  - acc[8] (32 persistent VGPRs) ELIMINATED: each iteration's contribution
//    is butterflied over the 16 c-lanes immediately (shfl_xor 1/2/4/8) and
//    RMW'd into a 512 B/wave LDS accumulator by the c==0 lanes. Wave-
//    private, in-order DS -> no barriers.
//  - Ch accumulators -> AGPRs under arch pressure (32 of 64); leftover AGPR
//    absorbs any spill as accvgpr moves (not scratch).
// LDS = 32 (W1a) + 32 (W2) + 8 x 0.5 (accw) = 68 KB -> 2 blocks/CU fit both
// LDS (136 <= 160) and regs (2 x 8 waves x 128 = exactly 512/SIMD).
// Body math = R17's verified operand-swap design (absmax 0.5).
// ---------------------------------------------------------------------------
__global__ __launch_bounds__(512, 4) void main_kernel(
    const float* __restrict__ query_emb,
    const float* __restrict__ refer_embs, const float* __restrict__ refer_r,
    const float* __restrict__ start_embs, const float* __restrict__ b2,
    const float* __restrict__ qproj, const unsigned short* __restrict__ w1a_t,
    const unsigned short* __restrict__ w2_t, float* __restrict__ out)
{
  __shared__ unsigned short lds_w1a[128 * 128];   // 32 KB
  __shared__ unsigned short lds_w2[128 * 128];    // 32 KB
  __shared__ float accw[8][128];                  // 512 B per wave

  const int tid  = threadIdx.x;
  const int wave = tid >> 6;
  const int lane = tid & 63;
  const int g    = lane >> 4;   // 0..3
  const int c    = lane & 15;   // r-lane / weight-row-lane

  { // stage weight tables (linear uint4 copy; layout pre-applied in ws)
    const uint4* s1 = reinterpret_cast<const uint4*>(w1a_t);
    const uint4* s2 = reinterpret_cast<const uint4*>(w2_t);
    uint4* d1 = reinterpret_cast<uint4*>(lds_w1a);
    uint4* d2 = reinterpret_cast<uint4*>(lds_w2);
    #pragma unroll
    for (int i = 0; i < 4; ++i) {
      d1[tid + 512 * i] = s1[tid + 512 * i];
      d2[tid + 512 * i] = s2[tid + 512 * i];
    }
  }
  __syncthreads();   // the ONLY barrier

  const int swc = (c & 7) << 3;
  const int b = blockIdx.x * 8 + wave;  // this wave's b
  float* myacc = accw[wave];

  // zero the wave accumulator (wave-private, in-order DS)
  myacc[lane] = 0.f;
  myacc[lane + 64] = 0.f;

  union U16x8 { unsigned int u[4]; s16x8 v; };

  for (int it = 0; it < 4; ++it) {
    const size_t rowoff = ((size_t)b * RR + it * 16 + c) * DIMD + 4 * g;
    const float* rp = refer_r    + rowoff;
    const float* ep = refer_embs + rowoff;
    const float* sp = start_embs + rowoff;

    unsigned int bp[16];   // packed bias (ev - sv - rv), bf16 pairs

    // ---- GEMM1: Ch[k=16nt+4g+reg, r=c] = W1a x rr + qproj  (Ch -> AGPR)
    f32x4 Ch[8];
    #pragma unroll
    for (int nt = 0; nt < 8; ++nt)
      Ch[nt] = *reinterpret_cast<const f32x4*>(qproj + (size_t)b * DIMD + 16 * nt + 4 * g);

    #pragma unroll
    for (int ck = 0; ck < 4; ++ck) {
      const float4 rv0 = *reinterpret_cast<const float4*>(rp + 32 * ck);
      const float4 rv1 = *reinterpret_cast<const float4*>(rp + 32 * ck + 16);
      const float4 ev0 = *reinterpret_cast<const float4*>(ep + 32 * ck);
      const float4 ev1 = *reinterpret_cast<const float4*>(ep + 32 * ck + 16);
      const float4 sv0 = *reinterpret_cast<const float4*>(sp + 32 * ck);
      const float4 sv1 = *reinterpret_cast<const float4*>(sp + 32 * ck + 16);
      U16x8 af;
      af.u[0] = pk2(rv0.x, rv0.y); af.u[1] = pk2(rv0.z, rv0.w);
      af.u[2] = pk2(rv1.x, rv1.y); af.u[3] = pk2(rv1.z, rv1.w);
      bp[4 * ck + 0] = pk2(ev0.x - sv0.x - rv0.x, ev0.y - sv0.y - rv0.y);
      bp[4 * ck + 1] = pk2(ev0.z - sv0.z - rv0.z, ev0.w - sv0.w - rv0.w);
      bp[4 * ck + 2] = pk2(ev1.x - sv1.x - rv1.x, ev1.y - sv1.y - rv1.y);
      bp[4 * ck + 3] = pk2(ev1.z - sv1.z - rv1.z, ev1.w - sv1.w - rv1.w);
      #pragma unroll
      for (int nt = 0; nt < 8; ++nt) {
        s16x8 wf = *reinterpret_cast<const s16x8*>(
            &lds_w1a[(nt * 16 + c) * DIMD + ((ck * 32 + g * 8) ^ swc)]);
        Ch[nt] = __builtin_amdgcn_mfma_f32_16x16x32_bf16(wf, af.v, Ch[nt], 0, 0, 0);
      }
      __builtin_amdgcn_sched_barrier(0);   // bound hoisting / liveness
    }

    // ---- relu + pack h (in-lane; layout matches GEMM2 B-frag; frees Ch)
    unsigned int hpk[16];
    #pragma unroll
    for (int nt = 0; nt < 8; ++nt) {
      hpk[2 * nt + 0] = pk2(fmaxf(Ch[nt][0], 0.f), fmaxf(Ch[nt][1], 0.f));
      hpk[2 * nt + 1] = pk2(fmaxf(Ch[nt][2], 0.f), fmaxf(Ch[nt][3], 0.f));
    }

    // ---- GEMM2 in 2-nt groups: MFMA -> bias-dot -> butterfly -> LDS RMW
    #pragma unroll
    for (int ntg = 0; ntg < 4; ++ntg) {
      f32x4 Ca0 = *reinterpret_cast<const f32x4*>(b2 + 32 * ntg + 4 * g);
      f32x4 Ca1 = *reinterpret_cast<const f32x4*>(b2 + 32 * ntg + 16 + 4 * g);
      #pragma unroll
      for (int ck = 0; ck < 4; ++ck) {
        U16x8 hf;
        hf.u[0] = hpk[4 * ck + 0]; hf.u[1] = hpk[4 * ck + 1];
        hf.u[2] = hpk[4 * ck + 2]; hf.u[3] = hpk[4 * ck + 3];
        s16x8 w0 = *reinterpret_cast<const s16x8*>(
            &lds_w2[((2 * ntg) * 16 + c) * DIMD + ((ck * 32 + g * 8) ^ swc)]);
        s16x8 w1 = *reinterpret_cast<const s16x8*>(
            &lds_w2[((2 * ntg + 1) * 16 + c) * DIMD + ((ck * 32 + g * 8) ^ swc)]);
        Ca0 = __builtin_amdgcn_mfma_f32_16x16x32_bf16(w0, hf.v, Ca0, 0, 0, 0);
        Ca1 = __builtin_amdgcn_mfma_f32_16x16x32_bf16(w1, hf.v, Ca1, 0, 0, 0);
      }
      float s[8];
      s[0] = Ca0[0] * bflo(bp[4 * ntg + 0]);
      s[1] = Ca0[1] * bfhi(bp[4 * ntg + 0]);
      s[2] = Ca0[2] * bflo(bp[4 * ntg + 1]);
      s[3] = Ca0[3] * bfhi(bp[4 * ntg + 1]);
      s[4] = Ca1[0] * bflo(bp[4 * ntg + 2]);
      s[5] = Ca1[1] * bfhi(bp[4 * ntg + 2]);
      s[6] = Ca1[2] * bflo(bp[4 * ntg + 3]);
      s[7] = Ca1[3] * bfhi(bp[4 * ntg + 3]);
      #pragma unroll
      for (int j = 0; j < 8; ++j) {
        s[j] += __shfl_xor(s[j], 1);
        s[j] += __shfl_xor(s[j], 2);
        s[j] += __shfl_xor(s[j], 4);
        s[j] += __shfl_xor(s[j], 8);
      }
      if (c == 0) {   // 4 lanes (g=0..3): RMW the wave accumulator
        f32x4* a0 = reinterpret_cast<f32x4*>(&myacc[16 * (2 * ntg) + 4 * g]);
        f32x4* a1 = reinterpret_cast<f32x4*>(&myacc[16 * (2 * ntg + 1) + 4 * g]);
        f32x4 v0 = *a0, v1 = *a1;
        v0[0] += s[0]; v0[1] += s[1]; v0[2] += s[2]; v0[3] += s[3];
        v1[0] += s[4]; v1[1] += s[5]; v1[2] += s[6]; v1[3] += s[7];
        *a0 = v0; *a1 = v1;
      }
      __builtin_amdgcn_sched_barrier(0);
    }
  }

  // ---- epilogue: c==0 lanes (g=0..3) read accw and write out
  if (c == 0) {
    #pragma unroll
    for (int nt = 0; nt < 8; ++nt) {
      const size_t o = (size_t)b * DIMD + 16 * nt + 4 * g;
      const float4 qe = *reinterpret_cast<const float4*>(query_emb + o);
      const f32x4 a = *reinterpret_cast<const f32x4*>(&myacc[16 * nt + 4 * g]);
      float4 r;
      r.x = qe.x + a[0]; r.y = qe.y + a[1];
      r.z = qe.z + a[2]; r.w = qe.w + a[3];
      *reinterpret_cast<float4*>(out + o) = r;
    }
  }
}

extern "C" void kernel_launch(void* const* d_in, const int* in_sizes, int n_in,
                              void* d_out, int out_size, void* d_ws, size_t ws_size,
                              hipStream_t stream) {
  const float* query_emb  = (const float*)d_in[0];
  const float* offset_emb = (const float*)d_in[1];
  const float* refer_embs = (const float*)d_in[2];
  const float* query_r    = (const float*)d_in[3];
  const float* refer_r    = (const float*)d_in[4];
  const float* start_embs = (const float*)d_in[5];
  const float* W1 = (const float*)d_in[6];
  const float* b1 = (const float*)d_in[7];
  const float* W2 = (const float*)d_in[8];
  const float* b2 = (const float*)d_in[9];
  float* out = (float*)d_out;

  float* qproj = (float*)d_ws;                       // 4096*128 f32 = 2 MB
  unsigned short* w1a_t =
      (unsigned short*)((char*)d_ws + (size_t)BTOT * DIMD * sizeof(float));
  unsigned short* w2_t = w1a_t + 128 * 128;          // +32 KB each

  hipLaunchKernelGGL(prep_kernel, dim3(512), dim3(256), 0, stream,
                     W1, b1, query_r, W2, offset_emb, qproj, w1a_t, w2_t, out);
  hipLaunchKernelGGL(main_kernel, dim3(512), dim3(512), 0, stream,
                     query_emb, refer_embs, refer_r, start_embs,
                     b2, qproj, w1a_t, w2_t, out);
}

// Round 22
// 133.619 us; speedup vs baseline: 1.3463x; 1.3463x over previous
//
#include <hip/hip_runtime.h>
#include <hip/hip_bf16.h>
#include <stdint.h>

#define BTOT 4096
#define RR   64
#define DIMD 128

typedef short s16x8 __attribute__((ext_vector_type(8)));
typedef float f32x4 __attribute__((ext_vector_type(4)));

__device__ __forceinline__ unsigned short f2bf(float x) {
  __hip_bfloat16 h = __float2bfloat16(x);
  return __builtin_bit_cast(unsigned short, h);
}
__device__ __forceinline__ unsigned int pk2(float lo, float hi) {
  return ((unsigned int)f2bf(hi) << 16) | (unsigned int)f2bf(lo);
}

// ---------------------------------------------------------------------------
// Pre-kernel: qproj[b,k] = sum_d query_r[b,d]*W1[k,128+d] + b1[k]  (fp32),
// offset_emb passthrough, and blocks 0/1 emit PERMUTED+swizzled bf16 copies
// of W1a / W2 into ws. d-permutation pi(s) = 32*(s>>5) + 16*((s>>2)&1) +
// 4*((s>>3)&3) + (s&3); bank-XOR: addr = k*128 + (s ^ ((k&7)<<3)).
// [layout verified: R16-R21 passed absmax 0.5]
// ---------------------------------------------------------------------------
__global__ __launch_bounds__(256) void prep_kernel(
    const float* __restrict__ W1, const float* __restrict__ b1,
    const float* __restrict__ query_r, const float* __restrict__ W2,
    const float* __restrict__ offset_emb,
    float* __restrict__ qproj, unsigned short* __restrict__ w1a_t,
    unsigned short* __restrict__ w2_t, float* __restrict__ out)
{
  __shared__ float w1b[128 * 132];   // +4 pad
  __shared__ float qrs[256];
  const int tid = threadIdx.x;

  { // offset_emb passthrough (1 float4 per thread; 512 blocks cover 4096x128)
    const size_t ob = (size_t)blockIdx.x * 8 * DIMD + (size_t)tid * 4;
    *reinterpret_cast<float4*>(out + (size_t)BTOT * DIMD + ob) =
        *reinterpret_cast<const float4*>(offset_emb + ob);
  }
  { // stage W1b fp32 into padded LDS
    const int k = tid >> 1, d0 = (tid & 1) * 64;
    const float* src = W1 + k * 256 + 128 + d0;
    float* dst = &w1b[k * 132 + d0];
    #pragma unroll
    for (int i = 0; i < 64; i += 4)
      *reinterpret_cast<float4*>(dst + i) = *reinterpret_cast<const float4*>(src + i);
  }
  if (blockIdx.x < 2) { // permuted + swizzled bf16 weight tables
    const float* Wsrc = (blockIdx.x == 0) ? W1 : W2;
    unsigned short* dstw = (blockIdx.x == 0) ? w1a_t : w2_t;
    const int stride = (blockIdx.x == 0) ? 256 : 128;
    for (int i = tid; i < 128 * 128; i += 256) {
      const int k = i >> 7, s = i & 127;
      const int d = 32 * (s >> 5) + 16 * ((s >> 2) & 1) + 4 * ((s >> 3) & 3) + (s & 3);
      dstw[k * 128 + (s ^ ((k & 7) << 3))] = f2bf(Wsrc[k * stride + d]);
    }
  }
  __syncthreads();

  const int b0 = blockIdx.x * 8;
  const int k = tid & 127, bh = tid >> 7;
  for (int p = 0; p < 4; ++p) {
    const int b = b0 + p * 2;
    qrs[tid] = query_r[(size_t)(b + bh) * DIMD + k];
    __syncthreads();
    float acc = b1[k];
    const float* qq = &qrs[bh * 128];
    const float* wr = &w1b[k * 132];
    #pragma unroll
    for (int d = 0; d < 128; d += 4) {
      float4 wv = *reinterpret_cast<const float4*>(wr + d);
      float4 qv = *reinterpret_cast<const float4*>(qq + d);
      acc = fmaf(wv.x, qv.x, acc); acc = fmaf(wv.y, qv.y, acc);
      acc = fmaf(wv.z, qv.z, acc); acc = fmaf(wv.w, qv.w, acc);
    }
    qproj[(size_t)(b + bh) * DIMD + k] = acc;
    __syncthreads();
  }
}

// ---------------------------------------------------------------------------
// Main kernel: 512 blocks x 512 threads (8 waves), each wave owns ONE b.
// R21 CONFIRMED the AGPR occupancy model: VGPR=64 -> 16 waves/CU (43%) and
// 2.8 TB/s delivered -- but the squeeze spilled ~130 MB (bp[16] + transient
// overlap exceeded 64). This round removes that pressure:
//  - GEMM1 loads ONLY rv (2 float4/quarter) -> af pack -> MFMA. No bias
//    computation, no ev/sv in GEMM1.
//  - GEMM2 RE-LOADS rv/ev/sv per quarter at the SAME addresses (hot in
//    L1/L2 ~300 cycles later; 16 waves/CU hide it) and computes bias in
//    f32 on the spot. bp[16] never exists; bias rounding error REMOVED.
//  - Accumulation stays in the 512 B/wave LDS accumulator (no acc regs);
//    Ch/Ca accumulators live in the AGPR half (40 of 64).
// Persistent VGPR ~30 (hpk16 + addressing), GEMM2 peak ~55 -> fits 64.
// LDS = 32 + 32 + 4 = 68 KB -> 2 blocks/CU (136 <= 160); regs 2 x 8 x
// (64+64) = 512/SIMD exactly (R21 proved this pairing DOES co-schedule).
// __launch_bounds__(512, 4) = the empirical 64-VGPR cap (R21-verified).
// ---------------------------------------------------------------------------
__global__ __launch_bounds__(512, 4) void main_kernel(
    const float* __restrict__ query_emb,
    const float* __restrict__ refer_embs, const float* __restrict__ refer_r,
    const float* __restrict__ start_embs, const float* __restrict__ b2,
    const float* __restrict__ qproj, const unsigned short* __restrict__ w1a_t,
    const unsigned short* __restrict__ w2_t, float* __restrict__ out)
{
  __shared__ unsigned short lds_w1a[128 * 128];   // 32 KB
  __shared__ unsigned short lds_w2[128 * 128];    // 32 KB
  __shared__ float accw[8][128];                  // 512 B per wave

  const int tid  = threadIdx.x;
  const int wave = tid >> 6;
  const int lane = tid & 63;
  const int g    = lane >> 4;   // 0..3
  const int c    = lane & 15;   // r-lane / weight-row-lane

  { // stage weight tables (linear uint4 copy; layout pre-applied in ws)
    const uint4* s1 = reinterpret_cast<const uint4*>(w1a_t);
    const uint4* s2 = reinterpret_cast<const uint4*>(w2_t);
    uint4* d1 = reinterpret_cast<uint4*>(lds_w1a);
    uint4* d2 = reinterpret_cast<uint4*>(lds_w2);
    #pragma unroll
    for (int i = 0; i < 4; ++i) {
      d1[tid + 512 * i] = s1[tid + 512 * i];
      d2[tid + 512 * i] = s2[tid + 512 * i];
    }
  }
  __syncthreads();   // the ONLY barrier

  const int swc = (c & 7) << 3;
  const int b = blockIdx.x * 8 + wave;  // this wave's b
  float* myacc = accw[wave];

  // zero the wave accumulator (wave-private, in-order DS)
  myacc[lane] = 0.f;
  myacc[lane + 64] = 0.f;

  union U16x8 { unsigned int u[4]; s16x8 v; };

  for (int it = 0; it < 4; ++it) {
    const size_t rowoff = ((size_t)b * RR + it * 16 + c) * DIMD + 4 * g;
    const float* rp = refer_r    + rowoff;
    const float* ep = refer_embs + rowoff;
    const float* sp = start_embs + rowoff;

    // ---- GEMM1: Ch[k=16nt+4g+reg, r=c] = W1a x rr + qproj  (Ch -> AGPR)
    f32x4 Ch[8];
    #pragma unroll
    for (int nt = 0; nt < 8; ++nt)
      Ch[nt] = *reinterpret_cast<const f32x4*>(qproj + (size_t)b * DIMD + 16 * nt + 4 * g);

    #pragma unroll
    for (int ck = 0; ck < 4; ++ck) {
      const float4 rv0 = *reinterpret_cast<const float4*>(rp + 32 * ck);
      const float4 rv1 = *reinterpret_cast<const float4*>(rp + 32 * ck + 16);
      U16x8 af;
      af.u[0] = pk2(rv0.x, rv0.y); af.u[1] = pk2(rv0.z, rv0.w);
      af.u[2] = pk2(rv1.x, rv1.y); af.u[3] = pk2(rv1.z, rv1.w);
      #pragma unroll
      for (int nt = 0; nt < 8; ++nt) {
        s16x8 wf = *reinterpret_cast<const s16x8*>(
            &lds_w1a[(nt * 16 + c) * DIMD + ((ck * 32 + g * 8) ^ swc)]);
        Ch[nt] = __builtin_amdgcn_mfma_f32_16x16x32_bf16(wf, af.v, Ch[nt], 0, 0, 0);
      }
      __builtin_amdgcn_sched_barrier(0);   // bound liveness to one quarter
    }

    // ---- relu + pack h (in-lane; layout matches GEMM2 B-frag; frees Ch)
    unsigned int hpk[16];
    #pragma unroll
    for (int nt = 0; nt < 8; ++nt) {
      hpk[2 * nt + 0] = pk2(fmaxf(Ch[nt][0], 0.f), fmaxf(Ch[nt][1], 0.f));
      hpk[2 * nt + 1] = pk2(fmaxf(Ch[nt][2], 0.f), fmaxf(Ch[nt][3], 0.f));
    }

    // ---- GEMM2 in 2-nt groups; bias RE-LOADED per quarter (f32, on the
    //      spot -- addresses identical to GEMM1's, L1/L2-hot)
    #pragma unroll
    for (int ntg = 0; ntg < 4; ++ntg) {
      // issue bias loads early; latency covered by the 8 MFMAs below
      const float4 rv0 = *reinterpret_cast<const float4*>(rp + 32 * ntg);
      const float4 rv1 = *reinterpret_cast<const float4*>(rp + 32 * ntg + 16);
      const float4 ev0 = *reinterpret_cast<const float4*>(ep + 32 * ntg);
      const float4 ev1 = *reinterpret_cast<const float4*>(ep + 32 * ntg + 16);
      const float4 sv0 = *reinterpret_cast<const float4*>(sp + 32 * ntg);
      const float4 sv1 = *reinterpret_cast<const float4*>(sp + 32 * ntg + 16);

      f32x4 Ca0 = *reinterpret_cast<const f32x4*>(b2 + 32 * ntg + 4 * g);
      f32x4 Ca1 = *reinterpret_cast<const f32x4*>(b2 + 32 * ntg + 16 + 4 * g);
      #pragma unroll
      for (int ck = 0; ck < 4; ++ck) {
        U16x8 hf;
        hf.u[0] = hpk[4 * ck + 0]; hf.u[1] = hpk[4 * ck + 1];
        hf.u[2] = hpk[4 * ck + 2]; hf.u[3] = hpk[4 * ck + 3];
        s16x8 w0 = *reinterpret_cast<const s16x8*>(
            &lds_w2[((2 * ntg) * 16 + c) * DIMD + ((ck * 32 + g * 8) ^ swc)]);
        s16x8 w1 = *reinterpret_cast<const s16x8*>(
            &lds_w2[((2 * ntg + 1) * 16 + c) * DIMD + ((ck * 32 + g * 8) ^ swc)]);
        Ca0 = __builtin_amdgcn_mfma_f32_16x16x32_bf16(w0, hf.v, Ca0, 0, 0, 0);
        Ca1 = __builtin_amdgcn_mfma_f32_16x16x32_bf16(w1, hf.v, Ca1, 0, 0, 0);
      }
      float s[8];
      s[0] = Ca0[0] * (ev0.x - sv0.x - rv0.x);
      s[1] = Ca0[1] * (ev0.y - sv0.y - rv0.y);
      s[2] = Ca0[2] * (ev0.z - sv0.z - rv0.z);
      s[3] = Ca0[3] * (ev0.w - sv0.w - rv0.w);
      s[4] = Ca1[0] * (ev1.x - sv1.x - rv1.x);
      s[5] = Ca1[1] * (ev1.y - sv1.y - rv1.y);
      s[6] = Ca1[2] * (ev1.z - sv1.z - rv1.z);
      s[7] = Ca1[3] * (ev1.w - sv1.w - rv1.w);
      #pragma unroll
      for (int j = 0; j < 8; ++j) {
        s[j] += __shfl_xor(s[j], 1);
        s[j] += __shfl_xor(s[j], 2);
        s[j] += __shfl_xor(s[j], 4);
        s[j] += __shfl_xor(s[j], 8);
      }
      if (c == 0) {   // 4 lanes (g=0..3): RMW the wave accumulator
        f32x4* a0 = reinterpret_cast<f32x4*>(&myacc[16 * (2 * ntg) + 4 * g]);
        f32x4* a1 = reinterpret_cast<f32x4*>(&myacc[16 * (2 * ntg + 1) + 4 * g]);
        f32x4 v0 = *a0, v1 = *a1;
        v0[0] += s[0]; v0[1] += s[1]; v0[2] += s[2]; v0[3] += s[3];
        v1[0] += s[4]; v1[1] += s[5]; v1[2] += s[6]; v1[3] += s[7];
        *a0 = v0; *a1 = v1;
      }
      __builtin_amdgcn_sched_barrier(0);
    }
  }

  // ---- epilogue: c==0 lanes (g=0..3) read accw and write out
  if (c == 0) {
    #pragma unroll
    for (int nt = 0; nt < 8; ++nt) {
      const size_t o = (size_t)b * DIMD + 16 * nt + 4 * g;
      const float4 qe = *reinterpret_cast<const float4*>(query_emb + o);
      const f32x4 a = *reinterpret_cast<const f32x4*>(&myacc[16 * nt + 4 * g]);
      float4 r;
      r.x = qe.x + a[0]; r.y = qe.y + a[1];
      r.z = qe.z + a[2]; r.w = qe.w + a[3];
      *reinterpret_cast<float4*>(out + o) = r;
    }
  }
}

extern "C" void kernel_launch(void* const* d_in, const int* in_sizes, int n_in,
                              void* d_out, int out_size, void* d_ws, size_t ws_size,
                              hipStream_t stream) {
  const float* query_emb  = (const float*)d_in[0];
  const float* offset_emb = (const float*)d_in[1];
  const float* refer_embs = (const float*)d_in[2];
  const float* query_r    = (const float*)d_in[3];
  const float* refer_r    = (const float*)d_in[4];
  const float* start_embs = (const float*)d_in[5];
  const float* W1 = (const float*)d_in[6];
  const float* b1 = (const float*)d_in[7];
  const float* W2 = (const float*)d_in[8];
  const float* b2 = (const float*)d_in[9];
  float* out = (float*)d_out;

  float* qproj = (float*)d_ws;                       // 4096*128 f32 = 2 MB
  unsigned short* w1a_t =
      (unsigned short*)((char*)d_ws + (size_t)BTOT * DIMD * sizeof(float));
  unsigned short* w2_t = w1a_t + 128 * 128;          // +32 KB each

  hipLaunchKernelGGL(prep_kernel, dim3(512), dim3(256), 0, stream,
                     W1, b1, query_r, W2, offset_emb, qproj, w1a_t, w2_t, out);
  hipLaunchKernelGGL(main_kernel, dim3(512), dim3(512), 0, stream,
                     query_emb, refer_embs, refer_r, start_embs,
                     b2, qproj, w1a_t, w2_t, out);
}